// Round 3
// baseline (545.834 us; speedup 1.0000x reference)
//
#include <hip/hip_runtime.h>
#include <math.h>

typedef _Float16 f16;
typedef _Float16 f16x8 __attribute__((ext_vector_type(8)));
typedef _Float16 f16x4 __attribute__((ext_vector_type(4)));
typedef float f32x4 __attribute__((ext_vector_type(4)));

// Problem constants
#define NCLASS   128
#define ED       512        // E = FEAT*EMB
#define NROWS    131072     // N
#define EMBD     64
#define VDIM     32
#define TASKD    64
#define KCLUST   32

// ---- workspace byte layout (fast path): f16 weights + stats ----
#define OFF_W0H  0ull
#define OFF_W1H  (OFF_W0H + (size_t)ED*ED*2)
#define OFF_STATS (OFF_W1H + (size_t)ED*ED*2)

// float offsets inside the stats region
#define WS_CNT   0
#define WS_SSUM  128
#define WS_SSQ   (128 + 65536)
#define WS_SIMP  (128 + 2*65536)
#define WS_MEAN  (WS_SIMP + 128)
#define WS_MNORM (WS_MEAN + 65536)
#define WS_NC    (WS_MNORM + 65536)
#define WS_V     (WS_NC + 128)
#define STATS_FLOATS (WS_V + NCLASS*VDIM)
#define WS_NEEDED (OFF_STATS + (size_t)STATS_FLOATS*4)

// =====================================================================
// Prep: convert W0/W1 to f16, k-packed layout Wp[((k>>3)*512+n)*8+(k&7)].
// =====================================================================
__global__ __launch_bounds__(256) void kPrep(const float* __restrict__ W0,
                                             const float* __restrict__ W1,
                                             f16* __restrict__ w0h,
                                             f16* __restrict__ w1h)
{
    const int idx = blockIdx.x * 256 + threadIdx.x;    // 0 .. 2*512*512/8-1
    const int sel = idx >= (ED * ED / 8);
    const float* W = sel ? W1 : W0;
    f16* oh = sel ? w1h : w0h;
    const int e8 = idx & (ED * ED / 8 - 1);
    const int n  = e8 & 511;
    const int kb = e8 >> 9;             // 0..63
    f16x8 hv;
    #pragma unroll
    for (int j = 0; j < 8; ++j)
        hv[j] = (f16)W[(kb * 8 + j) * ED + n];
    *(f16x8*)(oh + (kb * ED + n) * 8) = hv;
}

// =====================================================================
// Fused kernel, round 7: row-split phase pipeline (T14 async-stage).
// R2 post-mortem: ~95 of 206 us was x-staging, latency-bound at 1.15 TB/s
// (16 loads/wave in flight = reg cap), unoverlapped with GEMM.
// Fix: split the 64-row tile into two 32-row halves. While GEMM1 runs on
// rows 0-31 (only accA=32 regs live), the rows 32-63 staging loads (32
// regs) are in flight underneath 128 MFMAs (~2.5K cy >> 900 cy HBM lat).
// Phases (4 barriers):
//   P1 stage r0-31 | P2 issue r32-63 loads + G1_A + write r32-63
//   P3 t-write r0-31 + G1_B | P4 t-write r32-63 | P5 G2 full + epilogue
// Cost: w0h is streamed twice per block (1.5 MB/block L2 traffic total,
// ~26 TB/s at target speed, under the 34.5 ceiling).
// LDS: one 64x512 f16 tile (64 KiB), XOR-swizzled as before -> 2 blocks/CU.
// =====================================================================
__global__ __launch_bounds__(512, 4) void kFused(
    const float* __restrict__ x,
    const int*   __restrict__ y,
    const f16*  __restrict__ w0h,
    const float* __restrict__ b0,
    const f16*  __restrict__ w1h,
    const float* __restrict__ b1,
    float* __restrict__ stats)
{
    __shared__ f16 Th[64 * 512];   // 65,536 B

    const int tid  = threadIdx.x;
    const int lane = tid & 63;
    const int wid  = tid >> 6;          // 0..7 = column group
    const int q    = lane >> 4;         // quad 0..3 -> k-sub-block
    const int ln   = lane & 15;
    const int ncol0 = wid * 64;

    const int cls   = blockIdx.x >> 4;
    const int shot0 = (blockIdx.x & 15) * 64;

// ---- fragment load/compute macros ----
#define LOADA2(a_, ks_, rb_) do {                                         \
    const int pkb_ = (((ks_) * 4 + q) ^ (ln & 7)) * 8;                    \
    _Pragma("unroll")                                                     \
    for (int rt_ = 0; rt_ < 2; ++rt_)                                     \
        a_[rt_] = *(const f16x8*)&Th[((rb_) + rt_ * 16 + ln) * 512 + pkb_]; \
    } while (0)

#define LOADA4(a_, ks_) do {                                              \
    const int pkb_ = (((ks_) * 4 + q) ^ (ln & 7)) * 8;                    \
    _Pragma("unroll")                                                     \
    for (int rt_ = 0; rt_ < 4; ++rt_)                                     \
        a_[rt_] = *(const f16x8*)&Th[(rt_ * 16 + ln) * 512 + pkb_];       \
    } while (0)

#define LOADB(b_, wp_, ks_) do {                                          \
    const int kb_ = ((ks_) * 4 + q) * ED + ncol0 + ln;                    \
    _Pragma("unroll")                                                     \
    for (int ct_ = 0; ct_ < 4; ++ct_)                                     \
        b_[ct_] = *(const f16x8*)((wp_) + (kb_ + ct_ * 16) * 8);          \
    } while (0)

#define DOMFMA2(a_, b_, acc_) do {                                        \
    _Pragma("unroll")                                                     \
    for (int ct_ = 0; ct_ < 4; ++ct_) {                                   \
        _Pragma("unroll")                                                 \
        for (int rt_ = 0; rt_ < 2; ++rt_)                                 \
            acc_[rt_ * 4 + ct_] = __builtin_amdgcn_mfma_f32_16x16x32_f16( \
                a_[rt_], b_[ct_], acc_[rt_ * 4 + ct_], 0, 0, 0);          \
    } } while (0)

#define DOMFMA4(a_, b_) do {                                              \
    _Pragma("unroll")                                                     \
    for (int ct_ = 0; ct_ < 4; ++ct_) {                                   \
        _Pragma("unroll")                                                 \
        for (int rt_ = 0; rt_ < 2; ++rt_) {                               \
            accA[rt_ * 4 + ct_] = __builtin_amdgcn_mfma_f32_16x16x32_f16( \
                a_[rt_], b_[ct_], accA[rt_ * 4 + ct_], 0, 0, 0);          \
            accB[rt_ * 4 + ct_] = __builtin_amdgcn_mfma_f32_16x16x32_f16( \
                a_[rt_ + 2], b_[ct_], accB[rt_ * 4 + ct_], 0, 0, 0);      \
        } } } while (0)

// 16 k-step ping-pong GEMM half (8 MFMA/ks). bA must hold (wp_, ks=0).
#define G1LOOP(acc_, wp_, rb_) do {                                       \
    _Pragma("unroll 1")                                                   \
    for (int ks = 0; ks < 14; ks += 2) {                                  \
        LOADB(bB, wp_, ks + 1);                                           \
        LOADA2(aH, ks, rb_);                                              \
        DOMFMA2(aH, bA, acc_);                                            \
        LOADB(bA, wp_, ks + 2);                                           \
        LOADA2(aH, ks + 1, rb_);                                          \
        DOMFMA2(aH, bB, acc_);                                            \
    }                                                                     \
    LOADB(bB, wp_, 15);                                                   \
    LOADA2(aH, 14, rb_);                                                  \
    DOMFMA2(aH, bA, acc_);                                                \
    LOADA2(aH, 15, rb_);                                                  \
    DOMFMA2(aH, bB, acc_);                                                \
    } while (0)

// write t = relu(acc+b0) for a 32-row half back into the LDS tile
#define TWRITE(acc_, rb_) do {                                            \
    _Pragma("unroll")                                                     \
    for (int ct_ = 0; ct_ < 4; ++ct_) {                                   \
        const int col_ = ncol0 + ct_ * 16 + ln;                           \
        const float bv_ = b0[col_];                                       \
        const int kbx_ = col_ >> 3, ko_ = col_ & 7;                       \
        _Pragma("unroll")                                                 \
        for (int rt_ = 0; rt_ < 2; ++rt_) {                               \
            _Pragma("unroll")                                             \
            for (int rg_ = 0; rg_ < 4; ++rg_) {                           \
                const int row_ = (rb_) + rt_ * 16 + q * 4 + rg_;          \
                const float t_ = fmaxf(acc_[rt_ * 4 + ct_][rg_] + bv_, 0.f); \
                Th[row_ * 512 + ((kbx_ ^ (row_ & 7)) << 3) + ko_] = (f16)t_; \
            } } } } while (0)

    f32x4 accA[8], accB[8];
    f16x8 aH[4], bA[4], bB[4];

    // ---- P1: stage x rows 0-31 as f16 ----
    #pragma unroll
    for (int i = 0; i < 8; ++i) {
        const int flat = tid + i * 512;         // rows 0..31
        const int row  = flat >> 7;             // 128 float4 per row
        const int f    = flat & 127;
        const long orig = (long)cls + 128L * (shot0 + row);
        const float4 xv = *(const float4*)(x + orig * ED + f * 4);
        f16x4 hv;
        hv[0] = (f16)xv.x; hv[1] = (f16)xv.y;
        hv[2] = (f16)xv.z; hv[3] = (f16)xv.w;
        const int ha = row * 512 + (((f >> 1) ^ (row & 7)) << 3) + ((f & 1) << 2);
        *(f16x4*)&Th[ha] = hv;
    }

    #pragma unroll
    for (int i = 0; i < 8; ++i) accA[i] = (f32x4){0.f, 0.f, 0.f, 0.f};

    LOADB(bA, w0h, 0);          // prefetch (no LDS dependency)
    __syncthreads();            // bar1: rows 0-31 ready

    // ---- P2: issue rows 32-63 loads, GEMM1 on rows 0-31, then write ----
    float4 sr[8];
    #pragma unroll
    for (int i = 0; i < 8; ++i) {
        const int flat = tid + (i + 8) * 512;   // rows 32..63
        const int row  = flat >> 7;
        const int f    = flat & 127;
        const long orig = (long)cls + 128L * (shot0 + row);
        sr[i] = *(const float4*)(x + orig * ED + f * 4);
    }

    G1LOOP(accA, w0h, 0);       // 128 MFMA hide the sr[] loads

    #pragma unroll
    for (int i = 0; i < 8; ++i) {
        const int flat = tid + (i + 8) * 512;
        const int row  = flat >> 7;
        const int f    = flat & 127;
        f16x4 hv;
        hv[0] = (f16)sr[i].x; hv[1] = (f16)sr[i].y;
        hv[2] = (f16)sr[i].z; hv[3] = (f16)sr[i].w;
        const int ha = row * 512 + (((f >> 1) ^ (row & 7)) << 3) + ((f & 1) << 2);
        *(f16x4*)&Th[ha] = hv;
    }

    LOADB(bA, w0h, 0);          // prefetch G1_B's first B across the barrier
    __syncthreads();            // bar2: rows 32-63 ready; all G1_A reads done

    // ---- P3: t-write rows 0-31 (frees accA), GEMM1 on rows 32-63 ----
    TWRITE(accA, 0);
    #pragma unroll
    for (int i = 0; i < 8; ++i) accB[i] = (f32x4){0.f, 0.f, 0.f, 0.f};
    G1LOOP(accB, w0h, 32);

    __syncthreads();            // bar3: all x reads done; t rows 0-31 in LDS

    // ---- P4: t-write rows 32-63; reset accumulators ----
    TWRITE(accB, 32);
    #pragma unroll
    for (int i = 0; i < 8; ++i) {
        accA[i] = (f32x4){0.f, 0.f, 0.f, 0.f};
        accB[i] = (f32x4){0.f, 0.f, 0.f, 0.f};
    }
    LOADB(bA, w1h, 0);          // prefetch GEMM2's first B across the barrier
    __syncthreads();            // bar4: full t-tile ready

    // ---- P5: GEMM2 full width (w1h streamed once) ----
    #pragma unroll 1
    for (int ks = 0; ks < 14; ks += 2) {
        LOADB(bB, w1h, ks + 1);
        LOADA4(aH, ks);
        DOMFMA4(aH, bA);
        LOADB(bA, w1h, ks + 2);
        LOADA4(aH, ks + 1);
        DOMFMA4(aH, bB);
    }
    LOADB(bB, w1h, 15);
    LOADA4(aH, 14);
    DOMFMA4(aH, bA);
    LOADA4(aH, 15);
    DOMFMA4(aH, bB);

    // ---- epilogue: per-class stats (all 64 rows are one class) ----
    const int clsY = y[(long)cls + 128L * shot0];
    float* cnt  = stats + WS_CNT;
    float* ssum = stats + WS_SSUM;
    float* ssq  = stats + WS_SSQ;
    #pragma unroll
    for (int ct = 0; ct < 4; ++ct) {
        const int col = ncol0 + ct * 16 + ln;
        const float bv = b1[col];
        float s = 0.f, qq = 0.f;
        #pragma unroll
        for (int rt = 0; rt < 2; ++rt)
            #pragma unroll
            for (int rg = 0; rg < 4; ++rg) {
                const float hA = accA[rt * 4 + ct][rg] + bv;
                const float hB = accB[rt * 4 + ct][rg] + bv;
                s += hA + hB; qq += hA * hA + hB * hB;
            }
        s  += __shfl_xor(s, 16);  qq += __shfl_xor(qq, 16);
        s  += __shfl_xor(s, 32);  qq += __shfl_xor(qq, 32);
        if (lane < 16) {
            atomicAdd(&ssum[clsY * ED + col], s);
            atomicAdd(&ssq [clsY * ED + col], qq);
        }
    }
    if (tid == 0) atomicAdd(&cnt[clsY], 64.0f);

#undef LOADA2
#undef LOADA4
#undef LOADB
#undef DOMFMA2
#undef DOMFMA4
#undef G1LOOP
#undef TWRITE
}

// =====================================================================
// Round-1 fp32 fallback (used only if ws_size is too small)
// =====================================================================
__device__ __forceinline__ int swz(int k, int r) { return k * 32 + (r ^ (k & 28)); }

__global__ __launch_bounds__(256) void kA(const float* __restrict__ x,
                                          const int* __restrict__ y,
                                          const float* __restrict__ W0,
                                          const float* __restrict__ b0,
                                          const float* __restrict__ W1,
                                          const float* __restrict__ b1,
                                          float* __restrict__ ws)
{
    __shared__ float lds[ED * 32];
    const int tid  = threadIdx.x;
    const int cls  = blockIdx.x & 127;
    const int seg  = blockIdx.x >> 7;
    const int base = seg * 32;
    {
        const int rr = tid >> 7;
        const int k4 = (tid & 127) * 4;
        for (int jj = 0; jj < 16; ++jj) {
            const int r = 2 * jj + rr;
            const long row = (long)cls + 128L * (base + r);
            const float4 xv = *(const float4*)(x + row * ED + k4);
            lds[swz(k4 + 0, r)] = xv.x;
            lds[swz(k4 + 1, r)] = xv.y;
            lds[swz(k4 + 2, r)] = xv.z;
            lds[swz(k4 + 3, r)] = xv.w;
        }
    }
    __syncthreads();
    const int c = tid;
    float acc0[32], acc1[32];
    #pragma unroll
    for (int r = 0; r < 32; ++r) { acc0[r] = 0.f; acc1[r] = 0.f; }
    #pragma unroll 2
    for (int k = 0; k < ED; ++k) {
        const float wa = W0[k * ED + c];
        const float wb = W0[k * ED + c + 256];
        #pragma unroll
        for (int rc = 0; rc < 32; rc += 4) {
            const float4 xv = *(const float4*)&lds[k * 32 + (rc ^ (k & 28))];
            acc0[rc+0] += xv.x * wa; acc1[rc+0] += xv.x * wb;
            acc0[rc+1] += xv.y * wa; acc1[rc+1] += xv.y * wb;
            acc0[rc+2] += xv.z * wa; acc1[rc+2] += xv.z * wb;
            acc0[rc+3] += xv.w * wa; acc1[rc+3] += xv.w * wb;
        }
    }
    const float ba = b0[c], bb = b0[c + 256];
    __syncthreads();
    #pragma unroll
    for (int rc = 0; rc < 32; rc += 4) {
        float4 v0, v1;
        v0.x = fmaxf(acc0[rc+0] + ba, 0.f); v0.y = fmaxf(acc0[rc+1] + ba, 0.f);
        v0.z = fmaxf(acc0[rc+2] + ba, 0.f); v0.w = fmaxf(acc0[rc+3] + ba, 0.f);
        v1.x = fmaxf(acc1[rc+0] + bb, 0.f); v1.y = fmaxf(acc1[rc+1] + bb, 0.f);
        v1.z = fmaxf(acc1[rc+2] + bb, 0.f); v1.w = fmaxf(acc1[rc+3] + bb, 0.f);
        *(float4*)&lds[c * 32 + (rc ^ (c & 28))] = v0;
        *(float4*)&lds[(c + 256) * 32 + (rc ^ (c & 28))] = v1;
    }
    __syncthreads();
    #pragma unroll
    for (int r = 0; r < 32; ++r) { acc0[r] = 0.f; acc1[r] = 0.f; }
    #pragma unroll 2
    for (int k = 0; k < ED; ++k) {
        const float wa = W1[k * ED + c];
        const float wb = W1[k * ED + c + 256];
        #pragma unroll
        for (int rc = 0; rc < 32; rc += 4) {
            const float4 tv = *(const float4*)&lds[k * 32 + (rc ^ (k & 28))];
            acc0[rc+0] += tv.x * wa; acc1[rc+0] += tv.x * wb;
            acc0[rc+1] += tv.y * wa; acc1[rc+1] += tv.y * wb;
            acc0[rc+2] += tv.z * wa; acc1[rc+2] += tv.z * wb;
            acc0[rc+3] += tv.w * wa; acc1[rc+3] += tv.w * wb;
        }
    }
    const float c0 = b1[c], c1 = b1[c + 256];
    #pragma unroll
    for (int r = 0; r < 32; ++r) { acc0[r] += c0; acc1[r] += c1; }
    const int y0 = y[(long)cls + 128L * base];
    bool uni = true;
    #pragma unroll
    for (int r = 1; r < 32; ++r) uni = uni && (y[(long)cls + 128L * (base + r)] == y0);
    float* cnt  = ws + WS_CNT;
    float* ssum = ws + WS_SSUM;
    float* ssq  = ws + WS_SSQ;
    if (uni) {
        float s0 = 0.f, q0 = 0.f, s1 = 0.f, q1 = 0.f;
        #pragma unroll
        for (int r = 0; r < 32; ++r) {
            s0 += acc0[r]; q0 += acc0[r] * acc0[r];
            s1 += acc1[r]; q1 += acc1[r] * acc1[r];
        }
        atomicAdd(&ssum[y0 * ED + c], s0);
        atomicAdd(&ssq [y0 * ED + c], q0);
        atomicAdd(&ssum[y0 * ED + c + 256], s1);
        atomicAdd(&ssq [y0 * ED + c + 256], q1);
        if (tid == 0) atomicAdd(&cnt[y0], 32.0f);
    } else {
        #pragma unroll
        for (int r = 0; r < 32; ++r) {
            const int yr = y[(long)cls + 128L * (base + r)];
            atomicAdd(&ssum[yr * ED + c], acc0[r]);
            atomicAdd(&ssq [yr * ED + c], acc0[r] * acc0[r]);
            atomicAdd(&ssum[yr * ED + c + 256], acc1[r]);
            atomicAdd(&ssq [yr * ED + c + 256], acc1[r] * acc1[r]);
        }
        if (tid == 0)
            for (int r = 0; r < 32; ++r)
                atomicAdd(&cnt[y[(long)cls + 128L * (base + r)]], 1.0f);
    }
}

// ---------------- Stage B1: per-class mean/var/mnorm + s/v MLP ----------------
__global__ __launch_bounds__(256) void kB1(const float* __restrict__ Ws,
                                           const float* __restrict__ bs,
                                           const float* __restrict__ Wv0,
                                           const float* __restrict__ bv0,
                                           const float* __restrict__ Wv1,
                                           const float* __restrict__ bv1,
                                           float* __restrict__ ws)
{
    __shared__ float sv[1025];
    __shared__ float red[256];
    __shared__ float sb[EMBD];
    __shared__ float pb[VDIM];
    const int cI = blockIdx.x, tid = threadIdx.x;
    const float* ssum = ws + WS_SSUM + cI * ED;
    const float* ssq  = ws + WS_SSQ  + cI * ED;
    const float cntv = ws[WS_CNT + cI];

    float nacc = 0.f;
    for (int e = tid; e < ED; e += 256) {
        const float m = ssum[e] / cntv;
        const float qv = ssq[e];
        const float var = (qv - cntv * m * m) / (cntv - 1.0f);
        sv[e] = var;
        sv[512 + e] = m;
        ws[WS_MEAN + cI * ED + e] = m;
        nacc += m * m;
    }
    if (tid == 0) {
        const float Ncv = (cntv - 1.0f) / 1023.0f;
        sv[1024] = Ncv;
        ws[WS_NC + cI] = Ncv;
    }
    red[tid] = nacc;
    __syncthreads();
    for (int off = 128; off > 0; off >>= 1) {
        if (tid < off) red[tid] += red[tid + off];
        __syncthreads();
    }
    const float inv = 1.0f / fmaxf(sqrtf(red[0]), 1e-7f);
    for (int e = tid; e < ED; e += 256)
        ws[WS_MNORM + cI * ED + e] = sv[512 + e] * inv;
    __syncthreads();

    // s = relu(sv @ Ws + bs): 256 threads = 64 outputs x 4 k-slices
    {
        const int o  = tid & 63;
        const int sl = tid >> 6;
        const int k0 = sl * 256;
        float a = 0.f;
        for (int k = k0; k < k0 + 256; ++k) a += sv[k] * Ws[k * EMBD + o];
        if (sl == 3) a += sv[1024] * Ws[1024 * EMBD + o];
        red[tid] = a;
    }
    __syncthreads();
    if (tid < EMBD) {
        const float a = red[tid] + red[tid + 64] + red[tid + 128] + red[tid + 192] + bs[tid];
        sb[tid] = fmaxf(a, 0.f);
    }
    __syncthreads();
    if (tid < VDIM) {
        float a = bv0[tid];
        for (int k = 0; k < EMBD; ++k) a += sb[k] * Wv0[k * VDIM + tid];
        pb[tid] = fmaxf(a, 0.f);
    }
    __syncthreads();
    if (tid < VDIM) {
        float a = bv1[tid];
        for (int k = 0; k < VDIM; ++k) a += pb[k] * Wv1[k * VDIM + tid];
        ws[WS_V + cI * VDIM + tid] = a;
    }
}

// ---------------- Stage B2: weighted pairwise-cos partial sums ----------------
__global__ __launch_bounds__(128) void kB2(float* __restrict__ ws)
{
    __shared__ float mi[ED];
    __shared__ float red[128];
    const int i = blockIdx.x, tid = threadIdx.x;
    const float* mn = ws + WS_MNORM;
    for (int e = tid; e < ED; e += 128) mi[e] = mn[i * ED + e];
    __syncthreads();
    float contrib = 0.f;
    if (tid > i) {
        const float* rowj = mn + tid * ED;
        float d = 0.f;
        for (int e = 0; e < ED; e += 4) {
            const float4 a = *(const float4*)&mi[e];
            const float4 b = *(const float4*)&rowj[e];
            d += a.x * b.x + a.y * b.y + a.z * b.z + a.w * b.w;
        }
        contrib = (float)(tid - i) * d;
    }
    red[tid] = contrib;
    __syncthreads();
    for (int off = 64; off > 0; off >>= 1) {
        if (tid < off) red[tid] += red[tid + off];
        __syncthreads();
    }
    if (tid == 0) ws[WS_SIMP + i] = red[0];
}

// ---------------- Stage B3: vv -> task -> cluster read-out ----------------
__global__ __launch_bounds__(128) void kB3(const float* __restrict__ W2,
                                           const float* __restrict__ b2,
                                           const float* __restrict__ mem,
                                           float* __restrict__ ws,
                                           float* __restrict__ out)
{
    __shared__ float vv[2 * VDIM + 2];
    __shared__ float task[TASKD];
    __shared__ float Cr[KCLUST];
    __shared__ float rsum;
    const int tid = threadIdx.x;
    const float* v = ws + WS_V;

    if (tid < VDIM) {
        float me = 0.f;
        for (int c = 0; c < NCLASS; ++c) me += v[c * VDIM + tid];
        me /= (float)NCLASS;
        float va = 0.f;
        for (int c = 0; c < NCLASS; ++c) {
            const float d = v[c * VDIM + tid] - me;
            va += d * d;
        }
        va /= (float)(NCLASS - 1);
        vv[tid] = va;
        vv[VDIM + tid] = me;
    }
    if (tid == 32 + VDIM) {
        float a = 0.f;
        for (int c = 0; c < NCLASS; ++c) a += ws[WS_NC + c];
        vv[2 * VDIM] = a / (float)NCLASS;
    }
    if (tid == 33 + VDIM) {
        float a = 0.f;
        for (int i = 0; i < NCLASS; ++i) a += ws[WS_SIMP + i];
        vv[2 * VDIM + 1] = a;
    }
    __syncthreads();
    if (tid < TASKD) {
        float a = b2[tid];
        for (int k = 0; k < 2 * VDIM + 2; ++k) a += vv[k] * W2[k * TASKD + tid];
        task[tid] = fmaxf(a, 0.f);
    }
    __syncthreads();
    if (tid < KCLUST) {
        float dd = 0.f;
        for (int e = 0; e < TASKD; ++e) {
            const float df = task[e] - mem[tid * TASKD + e];
            dd += df * df;
        }
        const float d = sqrtf(dd);
        Cr[tid] = 1.0f / (d + 1.0f);    // TEMP=1: (d+1)^-1
    }
    __syncthreads();
    if (tid == 0) {
        float a = 0.f;
        for (int k = 0; k < KCLUST; ++k) a += Cr[k];
        rsum = a;
    }
    __syncthreads();
    if (tid < TASKD) {
        float a = 0.f;
        for (int k = 0; k < KCLUST; ++k) a += (Cr[k] / rsum) * mem[k * TASKD + tid];
        out[tid] = a;
    }
}

extern "C" void kernel_launch(void* const* d_in, const int* in_sizes, int n_in,
                              void* d_out, int out_size, void* d_ws, size_t ws_size,
                              hipStream_t stream)
{
    const float* x   = (const float*)d_in[0];
    const int*   y   = (const int*)  d_in[1];
    const float* W0  = (const float*)d_in[2];
    const float* b0  = (const float*)d_in[3];
    const float* W1  = (const float*)d_in[4];
    const float* b1  = (const float*)d_in[5];
    const float* Ws  = (const float*)d_in[6];
    const float* bs  = (const float*)d_in[7];
    const float* Wv0 = (const float*)d_in[8];
    const float* bv0 = (const float*)d_in[9];
    const float* Wv1 = (const float*)d_in[10];
    const float* bv1 = (const float*)d_in[11];
    const float* W2  = (const float*)d_in[12];
    const float* b2  = (const float*)d_in[13];
    const float* mem = (const float*)d_in[14];
    float* out = (float*)d_out;

    if (ws_size >= WS_NEEDED) {
        char* wsb = (char*)d_ws;
        f16* w0h = (f16*)(wsb + OFF_W0H);
        f16* w1h = (f16*)(wsb + OFF_W1H);
        float* stats = (float*)(wsb + OFF_STATS);

        hipMemsetAsync(stats, 0, (size_t)WS_SIMP * sizeof(float), stream);
        hipLaunchKernelGGL(kPrep, dim3(2 * ED * ED / 8 / 256), dim3(256), 0, stream,
                           W0, W1, w0h, w1h);
        hipLaunchKernelGGL(kFused, dim3(NROWS / 64), dim3(512), 0, stream,
                           x, y, w0h, b0, w1h, b1, stats);
        hipLaunchKernelGGL(kB1, dim3(NCLASS), dim3(256), 0, stream, Ws, bs, Wv0, bv0, Wv1, bv1, stats);
        hipLaunchKernelGGL(kB2, dim3(NCLASS), dim3(128), 0, stream, stats);
        hipLaunchKernelGGL(kB3, dim3(1), dim3(128), 0, stream, W2, b2, mem, stats, out);
    } else {
        float* ws = (float*)d_ws;
        hipMemsetAsync(ws, 0, (size_t)WS_SIMP * sizeof(float), stream);
        hipLaunchKernelGGL(kA,  dim3(NROWS / 32), dim3(256), 0, stream, x, y, W0, b0, W1, b1, ws);
        hipLaunchKernelGGL(kB1, dim3(NCLASS), dim3(256), 0, stream, Ws, bs, Wv0, bv0, Wv1, bv1, ws);
        hipLaunchKernelGGL(kB2, dim3(NCLASS), dim3(128), 0, stream, ws);
        hipLaunchKernelGGL(kB3, dim3(1), dim3(128), 0, stream, W2, b2, mem, ws, out);
    }
}

// Round 4
// 518.049 us; speedup vs baseline: 1.0536x; 1.0536x over previous
//
#include <hip/hip_runtime.h>
#include <math.h>

typedef _Float16 f16;
typedef _Float16 f16x8 __attribute__((ext_vector_type(8)));
typedef _Float16 f16x4 __attribute__((ext_vector_type(4)));
typedef float f32x4 __attribute__((ext_vector_type(4)));

// Problem constants
#define NCLASS   128
#define ED       512        // E = FEAT*EMB
#define NROWS    131072     // N
#define EMBD     64
#define VDIM     32
#define TASKD    64
#define KCLUST   32

// ---- workspace byte layout (fast path): f16 weights + stats ----
#define OFF_W0H  0ull
#define OFF_W1H  (OFF_W0H + (size_t)ED*ED*2)
#define OFF_STATS (OFF_W1H + (size_t)ED*ED*2)

// float offsets inside the stats region
#define WS_CNT   0
#define WS_SSUM  128
#define WS_SSQ   (128 + 65536)
#define WS_SIMP  (128 + 2*65536)
#define WS_MEAN  (WS_SIMP + 128)
#define WS_MNORM (WS_MEAN + 65536)
#define WS_NC    (WS_MNORM + 65536)
#define WS_V     (WS_NC + 128)
#define STATS_FLOATS (WS_V + NCLASS*VDIM)
#define WS_NEEDED (OFF_STATS + (size_t)STATS_FLOATS*4)

// async global->LDS, 16B per lane. LDS dest = wave-uniform base + lane*16.
__device__ __forceinline__ void gload16(const void* g, void* l)
{
    __builtin_amdgcn_global_load_lds(
        (const __attribute__((address_space(1))) unsigned int*)g,
        (__attribute__((address_space(3))) unsigned int*)l, 16, 0, 0);
}

// =====================================================================
// Prep: convert W0/W1 to f16, k-packed layout Wp[((k>>3)*512+n)*8+(k&7)].
// =====================================================================
__global__ __launch_bounds__(256) void kPrep(const float* __restrict__ W0,
                                             const float* __restrict__ W1,
                                             f16* __restrict__ w0h,
                                             f16* __restrict__ w1h)
{
    const int idx = blockIdx.x * 256 + threadIdx.x;    // 0 .. 2*512*512/8-1
    const int sel = idx >= (ED * ED / 8);
    const float* W = sel ? W1 : W0;
    f16* oh = sel ? w1h : w0h;
    const int e8 = idx & (ED * ED / 8 - 1);
    const int n  = e8 & 511;
    const int kb = e8 >> 9;             // 0..63
    f16x8 hv;
    #pragma unroll
    for (int j = 0; j < 8; ++j)
        hv[j] = (f16)W[(kb * 8 + j) * ED + n];
    *(f16x8*)(oh + (kb * ED + n) * 8) = hv;
}

// =====================================================================
// Fused kernel, round 8: R2 structure + global_load_lds strip staging.
// R3 post-mortem: register-prefetch overlap was confiscated by regalloc
// (VGPR stayed 64 -> loads sunk). Fix: staging that uses NO registers.
//   - Sx = 8-row fp32 strip (16 KB). 8 strips; in strip s, wave w owns
//     row s*8+w: 2x global_load_lds (1 KB/wave each, zero VGPRs), a
//     per-wave s_waitcnt vmcnt(0) (no barrier -- wave converts only its
//     own row), then 2x {ds_read f32x4, cvt, ds_write f16x4} into the
//     XOR-swizzled tile. Flight = 16 waves x 2 KB = 32 KB/CU >> the
//     9.2 KB needed for BW-bound => staging at ~6 TB/s, not 1.15.
//   - LDS 64+16 = 80 KB/block, 2 blocks/CU exactly (160 KiB).
//   - G1 / TWRITE / G2 / epilogue identical to R2 (known 206 us base).
// =====================================================================
__global__ __launch_bounds__(512, 4) void kFused(
    const float* __restrict__ x,
    const int*   __restrict__ y,
    const f16*  __restrict__ w0h,
    const float* __restrict__ b0,
    const f16*  __restrict__ w1h,
    const float* __restrict__ b1,
    float* __restrict__ stats)
{
    __shared__ f16   Th[64 * 512];   // 65,536 B
    __shared__ float Sx[8 * 512];    // 16,384 B fp32 strip

    const int tid  = threadIdx.x;
    const int lane = tid & 63;
    const int wid  = tid >> 6;          // 0..7 = column group / strip row
    const int q    = lane >> 4;         // quad 0..3 -> k-sub-block
    const int ln   = lane & 15;
    const int ncol0 = wid * 64;

    const int cls   = blockIdx.x >> 4;
    const int shot0 = (blockIdx.x & 15) * 64;

#define LOADA(a_, ks_) do {                                               \
    const int pkb_ = (((ks_) * 4 + q) ^ (ln & 7)) * 8;                    \
    _Pragma("unroll")                                                     \
    for (int rt_ = 0; rt_ < 4; ++rt_)                                     \
        a_[rt_] = *(const f16x8*)&Th[(rt_ * 16 + ln) * 512 + pkb_];       \
    } while (0)

#define LOADB(b_, wp_, ks_) do {                                          \
    const int kb_ = ((ks_) * 4 + q) * ED + ncol0 + ln;                    \
    _Pragma("unroll")                                                     \
    for (int ct_ = 0; ct_ < 4; ++ct_)                                     \
        b_[ct_] = *(const f16x8*)((wp_) + (kb_ + ct_ * 16) * 8);          \
    } while (0)

#define DOMFMA(a_, b_) do {                                               \
    _Pragma("unroll")                                                     \
    for (int ct_ = 0; ct_ < 4; ++ct_) {                                   \
        _Pragma("unroll")                                                 \
        for (int rt_ = 0; rt_ < 4; ++rt_)                                 \
            acc[rt_ * 4 + ct_] = __builtin_amdgcn_mfma_f32_16x16x32_f16(  \
                a_[rt_], b_[ct_], acc[rt_ * 4 + ct_], 0, 0, 0);           \
    } } while (0)

    // ---- phase 0: stage x-tile via global_load_lds strips ----
    {
        const float* xbase = x + ((long)cls + 128L * shot0) * 512;
        float* srow = Sx + wid * 512;
        #pragma unroll 1
        for (int s = 0; s < 8; ++s) {
            const int r = s * 8 + wid;                 // tile row this wave owns
            const float* src = xbase + (long)r * (128L * 512);
            gload16(src + lane * 4,        srow);
            gload16(src + 256 + lane * 4,  srow + 256);
            asm volatile("s_waitcnt vmcnt(0)" ::: "memory");
            // convert own row into the XOR-swizzled f16 tile
            #pragma unroll
            for (int p = 0; p < 2; ++p) {
                const int fl = p * 64 + lane;          // float4 index 0..127
                const float4 v = *(const float4*)&srow[fl * 4];
                f16x4 hv;
                hv[0] = (f16)v.x; hv[1] = (f16)v.y;
                hv[2] = (f16)v.z; hv[3] = (f16)v.w;
                const int ha = r * 512 + (((fl >> 1) ^ (r & 7)) << 3) + ((fl & 1) << 2);
                *(f16x4*)&Th[ha] = hv;
            }
        }
    }

    f32x4 acc[16];
    #pragma unroll
    for (int i = 0; i < 16; ++i) acc[i] = (f32x4){0.f, 0.f, 0.f, 0.f};

    f16x8 aH[4], bA[4], bB[4];

    LOADB(bA, w0h, 0);          // prefetch (no LDS dependency)
    __syncthreads();            // full tile staged (drains lgkmcnt too)

    // ---- phase 1: GEMM1 ----
    #pragma unroll 1
    for (int ks = 0; ks < 14; ks += 2) {
        LOADB(bB, w0h, ks + 1);
        LOADA(aH, ks);
        DOMFMA(aH, bA);
        LOADB(bA, w0h, ks + 2);
        LOADA(aH, ks + 1);
        DOMFMA(aH, bB);
    }
    LOADB(bB, w0h, 15);
    LOADA(aH, 14);
    DOMFMA(aH, bA);
    LOADA(aH, 15);
    DOMFMA(aH, bB);

    __syncthreads();   // everyone done reading x-tile

    // ---- write t = relu(acc+b0) as f16 back into the same LDS tile ----
    // C/D layout (16x16): m = q*4 + reg, n = lane&15
    #pragma unroll
    for (int ct = 0; ct < 4; ++ct) {
        const int col = ncol0 + ct * 16 + ln;
        const float bv = b0[col];
        const int kbx = col >> 3, ko = col & 7;
        #pragma unroll
        for (int rt = 0; rt < 4; ++rt) {
            #pragma unroll
            for (int rg = 0; rg < 4; ++rg) {
                const int row = rt * 16 + q * 4 + rg;
                const float t = fmaxf(acc[rt * 4 + ct][rg] + bv, 0.f);
                Th[row * 512 + ((kbx ^ (row & 7)) << 3) + ko] = (f16)t;
            }
        }
    }

    #pragma unroll
    for (int i = 0; i < 16; ++i) acc[i] = (f32x4){0.f, 0.f, 0.f, 0.f};

    // prefetch GEMM2 B(0) across the barrier
    LOADB(bA, w1h, 0);
    __syncthreads();   // t-tile complete

    // ---- phase 2: GEMM2 ----
    #pragma unroll 1
    for (int ks = 0; ks < 14; ks += 2) {
        LOADB(bB, w1h, ks + 1);
        LOADA(aH, ks);
        DOMFMA(aH, bA);
        LOADB(bA, w1h, ks + 2);
        LOADA(aH, ks + 1);
        DOMFMA(aH, bB);
    }
    LOADB(bB, w1h, 15);
    LOADA(aH, 14);
    DOMFMA(aH, bA);
    LOADA(aH, 15);
    DOMFMA(aH, bB);

    // ---- epilogue: per-class stats (all 64 rows are one class) ----
    const int clsY = y[(long)cls + 128L * shot0];
    float* cnt  = stats + WS_CNT;
    float* ssum = stats + WS_SSUM;
    float* ssq  = stats + WS_SSQ;
    #pragma unroll
    for (int ct = 0; ct < 4; ++ct) {
        const int col = ncol0 + ct * 16 + ln;
        const float bv = b1[col];
        float s = 0.f, qq = 0.f;
        #pragma unroll
        for (int rt = 0; rt < 4; ++rt)
            #pragma unroll
            for (int rg = 0; rg < 4; ++rg) {
                const float h = acc[rt * 4 + ct][rg] + bv;
                s += h; qq += h * h;
            }
        s  += __shfl_xor(s, 16);  qq += __shfl_xor(qq, 16);
        s  += __shfl_xor(s, 32);  qq += __shfl_xor(qq, 32);
        if (lane < 16) {
            atomicAdd(&ssum[clsY * ED + col], s);
            atomicAdd(&ssq [clsY * ED + col], qq);
        }
    }
    if (tid == 0) atomicAdd(&cnt[clsY], 64.0f);

#undef LOADA
#undef LOADB
#undef DOMFMA
}

// =====================================================================
// Round-1 fp32 fallback (used only if ws_size is too small)
// =====================================================================
__device__ __forceinline__ int swz(int k, int r) { return k * 32 + (r ^ (k & 28)); }

__global__ __launch_bounds__(256) void kA(const float* __restrict__ x,
                                          const int* __restrict__ y,
                                          const float* __restrict__ W0,
                                          const float* __restrict__ b0,
                                          const float* __restrict__ W1,
                                          const float* __restrict__ b1,
                                          float* __restrict__ ws)
{
    __shared__ float lds[ED * 32];
    const int tid  = threadIdx.x;
    const int cls  = blockIdx.x & 127;
    const int seg  = blockIdx.x >> 7;
    const int base = seg * 32;
    {
        const int rr = tid >> 7;
        const int k4 = (tid & 127) * 4;
        for (int jj = 0; jj < 16; ++jj) {
            const int r = 2 * jj + rr;
            const long row = (long)cls + 128L * (base + r);
            const float4 xv = *(const float4*)(x + row * ED + k4);
            lds[swz(k4 + 0, r)] = xv.x;
            lds[swz(k4 + 1, r)] = xv.y;
            lds[swz(k4 + 2, r)] = xv.z;
            lds[swz(k4 + 3, r)] = xv.w;
        }
    }
    __syncthreads();
    const int c = tid;
    float acc0[32], acc1[32];
    #pragma unroll
    for (int r = 0; r < 32; ++r) { acc0[r] = 0.f; acc1[r] = 0.f; }
    #pragma unroll 2
    for (int k = 0; k < ED; ++k) {
        const float wa = W0[k * ED + c];
        const float wb = W0[k * ED + c + 256];
        #pragma unroll
        for (int rc = 0; rc < 32; rc += 4) {
            const float4 xv = *(const float4*)&lds[k * 32 + (rc ^ (k & 28))];
            acc0[rc+0] += xv.x * wa; acc1[rc+0] += xv.x * wb;
            acc0[rc+1] += xv.y * wa; acc1[rc+1] += xv.y * wb;
            acc0[rc+2] += xv.z * wa; acc1[rc+2] += xv.z * wb;
            acc0[rc+3] += xv.w * wa; acc1[rc+3] += xv.w * wb;
        }
    }
    const float ba = b0[c], bb = b0[c + 256];
    __syncthreads();
    #pragma unroll
    for (int rc = 0; rc < 32; rc += 4) {
        float4 v0, v1;
        v0.x = fmaxf(acc0[rc+0] + ba, 0.f); v0.y = fmaxf(acc0[rc+1] + ba, 0.f);
        v0.z = fmaxf(acc0[rc+2] + ba, 0.f); v0.w = fmaxf(acc0[rc+3] + ba, 0.f);
        v1.x = fmaxf(acc1[rc+0] + bb, 0.f); v1.y = fmaxf(acc1[rc+1] + bb, 0.f);
        v1.z = fmaxf(acc1[rc+2] + bb, 0.f); v1.w = fmaxf(acc1[rc+3] + bb, 0.f);
        *(float4*)&lds[c * 32 + (rc ^ (c & 28))] = v0;
        *(float4*)&lds[(c + 256) * 32 + (rc ^ (c & 28))] = v1;
    }
    __syncthreads();
    #pragma unroll
    for (int r = 0; r < 32; ++r) { acc0[r] = 0.f; acc1[r] = 0.f; }
    #pragma unroll 2
    for (int k = 0; k < ED; ++k) {
        const float wa = W1[k * ED + c];
        const float wb = W1[k * ED + c + 256];
        #pragma unroll
        for (int rc = 0; rc < 32; rc += 4) {
            const float4 tv = *(const float4*)&lds[k * 32 + (rc ^ (k & 28))];
            acc0[rc+0] += tv.x * wa; acc1[rc+0] += tv.x * wb;
            acc0[rc+1] += tv.y * wa; acc1[rc+1] += tv.y * wb;
            acc0[rc+2] += tv.z * wa; acc1[rc+2] += tv.z * wb;
            acc0[rc+3] += tv.w * wa; acc1[rc+3] += tv.w * wb;
        }
    }
    const float c0 = b1[c], c1 = b1[c + 256];
    #pragma unroll
    for (int r = 0; r < 32; ++r) { acc0[r] += c0; acc1[r] += c1; }
    const int y0 = y[(long)cls + 128L * base];
    bool uni = true;
    #pragma unroll
    for (int r = 1; r < 32; ++r) uni = uni && (y[(long)cls + 128L * (base + r)] == y0);
    float* cnt  = ws + WS_CNT;
    float* ssum = ws + WS_SSUM;
    float* ssq  = ws + WS_SSQ;
    if (uni) {
        float s0 = 0.f, q0 = 0.f, s1 = 0.f, q1 = 0.f;
        #pragma unroll
        for (int r = 0; r < 32; ++r) {
            s0 += acc0[r]; q0 += acc0[r] * acc0[r];
            s1 += acc1[r]; q1 += acc1[r] * acc1[r];
        }
        atomicAdd(&ssum[y0 * ED + c], s0);
        atomicAdd(&ssq [y0 * ED + c], q0);
        atomicAdd(&ssum[y0 * ED + c + 256], s1);
        atomicAdd(&ssq [y0 * ED + c + 256], q1);
        if (tid == 0) atomicAdd(&cnt[y0], 32.0f);
    } else {
        #pragma unroll
        for (int r = 0; r < 32; ++r) {
            const int yr = y[(long)cls + 128L * (base + r)];
            atomicAdd(&ssum[yr * ED + c], acc0[r]);
            atomicAdd(&ssq [yr * ED + c], acc0[r] * acc0[r]);
            atomicAdd(&ssum[yr * ED + c + 256], acc1[r]);
            atomicAdd(&ssq [yr * ED + c + 256], acc1[r] * acc1[r]);
        }
        if (tid == 0)
            for (int r = 0; r < 32; ++r)
                atomicAdd(&cnt[y[(long)cls + 128L * (base + r)]], 1.0f);
    }
}

// ---------------- Stage B1: per-class mean/var/mnorm + s/v MLP ----------------
__global__ __launch_bounds__(256) void kB1(const float* __restrict__ Ws,
                                           const float* __restrict__ bs,
                                           const float* __restrict__ Wv0,
                                           const float* __restrict__ bv0,
                                           const float* __restrict__ Wv1,
                                           const float* __restrict__ bv1,
                                           float* __restrict__ ws)
{
    __shared__ float sv[1025];
    __shared__ float red[256];
    __shared__ float sb[EMBD];
    __shared__ float pb[VDIM];
    const int cI = blockIdx.x, tid = threadIdx.x;
    const float* ssum = ws + WS_SSUM + cI * ED;
    const float* ssq  = ws + WS_SSQ  + cI * ED;
    const float cntv = ws[WS_CNT + cI];

    float nacc = 0.f;
    for (int e = tid; e < ED; e += 256) {
        const float m = ssum[e] / cntv;
        const float qv = ssq[e];
        const float var = (qv - cntv * m * m) / (cntv - 1.0f);
        sv[e] = var;
        sv[512 + e] = m;
        ws[WS_MEAN + cI * ED + e] = m;
        nacc += m * m;
    }
    if (tid == 0) {
        const float Ncv = (cntv - 1.0f) / 1023.0f;
        sv[1024] = Ncv;
        ws[WS_NC + cI] = Ncv;
    }
    red[tid] = nacc;
    __syncthreads();
    for (int off = 128; off > 0; off >>= 1) {
        if (tid < off) red[tid] += red[tid + off];
        __syncthreads();
    }
    const float inv = 1.0f / fmaxf(sqrtf(red[0]), 1e-7f);
    for (int e = tid; e < ED; e += 256)
        ws[WS_MNORM + cI * ED + e] = sv[512 + e] * inv;
    __syncthreads();

    // s = relu(sv @ Ws + bs): 256 threads = 64 outputs x 4 k-slices
    {
        const int o  = tid & 63;
        const int sl = tid >> 6;
        const int k0 = sl * 256;
        float a = 0.f;
        for (int k = k0; k < k0 + 256; ++k) a += sv[k] * Ws[k * EMBD + o];
        if (sl == 3) a += sv[1024] * Ws[1024 * EMBD + o];
        red[tid] = a;
    }
    __syncthreads();
    if (tid < EMBD) {
        const float a = red[tid] + red[tid + 64] + red[tid + 128] + red[tid + 192] + bs[tid];
        sb[tid] = fmaxf(a, 0.f);
    }
    __syncthreads();
    if (tid < VDIM) {
        float a = bv0[tid];
        for (int k = 0; k < EMBD; ++k) a += sb[k] * Wv0[k * VDIM + tid];
        pb[tid] = fmaxf(a, 0.f);
    }
    __syncthreads();
    if (tid < VDIM) {
        float a = bv1[tid];
        for (int k = 0; k < VDIM; ++k) a += pb[k] * Wv1[k * VDIM + tid];
        ws[WS_V + cI * VDIM + tid] = a;
    }
}

// ---------------- Stage B2: weighted pairwise-cos partial sums ----------------
__global__ __launch_bounds__(128) void kB2(float* __restrict__ ws)
{
    __shared__ float mi[ED];
    __shared__ float red[128];
    const int i = blockIdx.x, tid = threadIdx.x;
    const float* mn = ws + WS_MNORM;
    for (int e = tid; e < ED; e += 128) mi[e] = mn[i * ED + e];
    __syncthreads();
    float contrib = 0.f;
    if (tid > i) {
        const float* rowj = mn + tid * ED;
        float d = 0.f;
        for (int e = 0; e < ED; e += 4) {
            const float4 a = *(const float4*)&mi[e];
            const float4 b = *(const float4*)&rowj[e];
            d += a.x * b.x + a.y * b.y + a.z * b.z + a.w * b.w;
        }
        contrib = (float)(tid - i) * d;
    }
    red[tid] = contrib;
    __syncthreads();
    for (int off = 64; off > 0; off >>= 1) {
        if (tid < off) red[tid] += red[tid + off];
        __syncthreads();
    }
    if (tid == 0) ws[WS_SIMP + i] = red[0];
}

// ---------------- Stage B3: vv -> task -> cluster read-out ----------------
__global__ __launch_bounds__(128) void kB3(const float* __restrict__ W2,
                                           const float* __restrict__ b2,
                                           const float* __restrict__ mem,
                                           float* __restrict__ ws,
                                           float* __restrict__ out)
{
    __shared__ float vv[2 * VDIM + 2];
    __shared__ float task[TASKD];
    __shared__ float Cr[KCLUST];
    __shared__ float rsum;
    const int tid = threadIdx.x;
    const float* v = ws + WS_V;

    if (tid < VDIM) {
        float me = 0.f;
        for (int c = 0; c < NCLASS; ++c) me += v[c * VDIM + tid];
        me /= (float)NCLASS;
        float va = 0.f;
        for (int c = 0; c < NCLASS; ++c) {
            const float d = v[c * VDIM + tid] - me;
            va += d * d;
        }
        va /= (float)(NCLASS - 1);
        vv[tid] = va;
        vv[VDIM + tid] = me;
    }
    if (tid == 32 + VDIM) {
        float a = 0.f;
        for (int c = 0; c < NCLASS; ++c) a += ws[WS_NC + c];
        vv[2 * VDIM] = a / (float)NCLASS;
    }
    if (tid == 33 + VDIM) {
        float a = 0.f;
        for (int i = 0; i < NCLASS; ++i) a += ws[WS_SIMP + i];
        vv[2 * VDIM + 1] = a;
    }
    __syncthreads();
    if (tid < TASKD) {
        float a = b2[tid];
        for (int k = 0; k < 2 * VDIM + 2; ++k) a += vv[k] * W2[k * TASKD + tid];
        task[tid] = fmaxf(a, 0.f);
    }
    __syncthreads();
    if (tid < KCLUST) {
        float dd = 0.f;
        for (int e = 0; e < TASKD; ++e) {
            const float df = task[e] - mem[tid * TASKD + e];
            dd += df * df;
        }
        const float d = sqrtf(dd);
        Cr[tid] = 1.0f / (d + 1.0f);    // TEMP=1: (d+1)^-1
    }
    __syncthreads();
    if (tid == 0) {
        float a = 0.f;
        for (int k = 0; k < KCLUST; ++k) a += Cr[k];
        rsum = a;
    }
    __syncthreads();
    if (tid < TASKD) {
        float a = 0.f;
        for (int k = 0; k < KCLUST; ++k) a += (Cr[k] / rsum) * mem[k * TASKD + tid];
        out[tid] = a;
    }
}

extern "C" void kernel_launch(void* const* d_in, const int* in_sizes, int n_in,
                              void* d_out, int out_size, void* d_ws, size_t ws_size,
                              hipStream_t stream)
{
    const float* x   = (const float*)d_in[0];
    const int*   y   = (const int*)  d_in[1];
    const float* W0  = (const float*)d_in[2];
    const float* b0  = (const float*)d_in[3];
    const float* W1  = (const float*)d_in[4];
    const float* b1  = (const float*)d_in[5];
    const float* Ws  = (const float*)d_in[6];
    const float* bs  = (const float*)d_in[7];
    const float* Wv0 = (const float*)d_in[8];
    const float* bv0 = (const float*)d_in[9];
    const float* Wv1 = (const float*)d_in[10];
    const float* bv1 = (const float*)d_in[11];
    const float* W2  = (const float*)d_in[12];
    const float* b2  = (const float*)d_in[13];
    const float* mem = (const float*)d_in[14];
    float* out = (float*)d_out;

    if (ws_size >= WS_NEEDED) {
        char* wsb = (char*)d_ws;
        f16* w0h = (f16*)(wsb + OFF_W0H);
        f16* w1h = (f16*)(wsb + OFF_W1H);
        float* stats = (float*)(wsb + OFF_STATS);

        hipMemsetAsync(stats, 0, (size_t)WS_SIMP * sizeof(float), stream);
        hipLaunchKernelGGL(kPrep, dim3(2 * ED * ED / 8 / 256), dim3(256), 0, stream,
                           W0, W1, w0h, w1h);
        hipLaunchKernelGGL(kFused, dim3(NROWS / 64), dim3(512), 0, stream,
                           x, y, w0h, b0, w1h, b1, stats);
        hipLaunchKernelGGL(kB1, dim3(NCLASS), dim3(256), 0, stream, Ws, bs, Wv0, bv0, Wv1, bv1, stats);
        hipLaunchKernelGGL(kB2, dim3(NCLASS), dim3(128), 0, stream, stats);
        hipLaunchKernelGGL(kB3, dim3(1), dim3(128), 0, stream, W2, b2, mem, stats, out);
    } else {
        float* ws = (float*)d_ws;
        hipMemsetAsync(ws, 0, (size_t)WS_SIMP * sizeof(float), stream);
        hipLaunchKernelGGL(kA,  dim3(NROWS / 32), dim3(256), 0, stream, x, y, W0, b0, W1, b1, ws);
        hipLaunchKernelGGL(kB1, dim3(NCLASS), dim3(256), 0, stream, Ws, bs, Wv0, bv0, Wv1, bv1, ws);
        hipLaunchKernelGGL(kB2, dim3(NCLASS), dim3(128), 0, stream, ws);
        hipLaunchKernelGGL(kB3, dim3(1), dim3(128), 0, stream, W2, b2, mem, ws, out);
    }
}